// Round 1
// baseline (753.390 us; speedup 1.0000x reference)
//
#include <hip/hip_runtime.h>

static constexpr int N_NODES = 250000;
static constexpr int N_EDGES = 5000000;

// deg[n] = 1 (self-loop); counted up by k_deg.
__global__ void k_init(float* __restrict__ deg) {
    int n = blockIdx.x * blockDim.x + threadIdx.x;
    if (n < N_NODES) deg[n] = 1.0f;
}

__global__ void k_deg(const int* __restrict__ dst, float* __restrict__ deg) {
    int e = blockIdx.x * blockDim.x + threadIdx.x;
    if (e < N_EDGES) atomicAdd(&deg[dst[e]], 1.0f);
}

// dinv = rsqrt(deg); xs = x*dinv (pre-scaled source term);
// s initialized with the self-loop contribution x*dinv*dinv.
__global__ void k_node1(const float* __restrict__ x, const float* __restrict__ deg,
                        float* __restrict__ dinv, float* __restrict__ xs,
                        float* __restrict__ s) {
    int n = blockIdx.x * blockDim.x + threadIdx.x;
    if (n < N_NODES) {
        float di = rsqrtf(deg[n]);
        float xv = x[n];
        dinv[n] = di;
        xs[n] = xv * di;
        s[n]  = xv * di * di;
    }
}

// Layer-1 scalar aggregation: s[dst] += x[src]*dinv[src]*dinv[dst]
__global__ void k_sc1(const int* __restrict__ src, const int* __restrict__ dst,
                      const float* __restrict__ xs, const float* __restrict__ dinv,
                      float* __restrict__ s) {
    int e = blockIdx.x * blockDim.x + threadIdx.x;
    if (e < N_EDGES) {
        int si = src[e], di = dst[e];
        atomicAdd(&s[di], xs[si] * dinv[di]);
    }
}

// Per-node MLP: t = sum_k relu(s*W1[k]+b1[k])*W2[k];
// u = t*dinv (pre-scaled for edge pass); out init = b2 + t*dinv*dinv (self-loop).
__global__ void k_node2(const float* __restrict__ s, const float* __restrict__ dinv,
                        const float* __restrict__ W1, const float* __restrict__ b1,
                        const float* __restrict__ W2, const float* __restrict__ b2,
                        float* __restrict__ u, float* __restrict__ out) {
    int n = blockIdx.x * blockDim.x + threadIdx.x;
    if (n < N_NODES) {
        float sv = s[n];
        float acc = 0.0f;
        #pragma unroll
        for (int k = 0; k < 16; ++k) {
            float h = fmaf(sv, W1[k], b1[k]);
            h = fmaxf(h, 0.0f);
            acc = fmaf(h, W2[k], acc);
        }
        float di = dinv[n];
        u[n]   = acc * di;
        out[n] = b2[0] + acc * di * di;
    }
}

// Layer-2 scalar aggregation: out[dst] += t[src]*dinv[src]*dinv[dst]
__global__ void k_sc2(const int* __restrict__ src, const int* __restrict__ dst,
                      const float* __restrict__ u, const float* __restrict__ dinv,
                      float* __restrict__ out) {
    int e = blockIdx.x * blockDim.x + threadIdx.x;
    if (e < N_EDGES) {
        int si = src[e], di = dst[e];
        atomicAdd(&out[di], u[si] * dinv[di]);
    }
}

extern "C" void kernel_launch(void* const* d_in, const int* in_sizes, int n_in,
                              void* d_out, int out_size, void* d_ws, size_t ws_size,
                              hipStream_t stream) {
    const float* x  = (const float*)d_in[0];
    const int*   ei = (const int*)d_in[1];
    const float* W1 = (const float*)d_in[2];
    const float* b1 = (const float*)d_in[3];
    const float* W2 = (const float*)d_in[4];
    const float* b2 = (const float*)d_in[5];
    float* out = (float*)d_out;

    // edge_index is [2, E] row-major: row 0 = src, row 1 = dst.
    // JAX (x64 disabled) yields int32; harness passes integers as int*.
    const int* src = ei;
    const int* dst = ei + N_EDGES;

    // Workspace layout (4 MB total): deg (aliased as u after it dies), dinv, xs, s.
    float* deg  = (float*)d_ws;
    float* dinv = deg  + N_NODES;
    float* xs   = dinv + N_NODES;
    float* s    = xs   + N_NODES;
    float* u    = deg;   // deg is dead after k_node1

    const int TB = 256;
    const int gn = (N_NODES + TB - 1) / TB;
    const int ge = (N_EDGES + TB - 1) / TB;

    k_init <<<gn, TB, 0, stream>>>(deg);
    k_deg  <<<ge, TB, 0, stream>>>(dst, deg);
    k_node1<<<gn, TB, 0, stream>>>(x, deg, dinv, xs, s);
    k_sc1  <<<ge, TB, 0, stream>>>(src, dst, xs, dinv, s);
    k_node2<<<gn, TB, 0, stream>>>(s, dinv, W1, b1, W2, b2, u, out);
    k_sc2  <<<ge, TB, 0, stream>>>(src, dst, u, dinv, out);
}

// Round 2
// 171.066 us; speedup vs baseline: 4.4041x; 4.4041x over previous
//
#include <hip/hip_runtime.h>

static constexpr int N_NODES = 250000;
static constexpr int N_EDGES = 5000000;

// ---- fast path: counting-sort by dst>>8 into 256-node buckets ----
static constexpr int NB = 512;                              // partition blocks
static constexpr int CHUNK = (N_EDGES + NB - 1) / NB;       // 9766
static constexpr int BARR = 1024;                           // allocated bucket slots
static constexpr int NBUCK = (N_NODES + 255) / 256;         // 977

__global__ void k_hist(const int* __restrict__ dst, unsigned* __restrict__ hist) {
    __shared__ unsigned h[BARR];
    for (int j = threadIdx.x; j < BARR; j += 256) h[j] = 0;
    __syncthreads();
    int beg = blockIdx.x * CHUNK;
    int end = min(beg + CHUNK, N_EDGES);
    for (int e = beg + threadIdx.x; e < end; e += 256)
        atomicAdd(&h[((unsigned)dst[e]) >> 8], 1u);   // LDS atomic
    __syncthreads();
    unsigned* o = hist + (size_t)blockIdx.x * BARR;
    for (int j = threadIdx.x; j < BARR; j += 256) o[j] = h[j];
}

__global__ void k_total(const unsigned* __restrict__ hist, unsigned* __restrict__ total) {
    int b = blockIdx.x * 256 + threadIdx.x;
    if (b >= BARR) return;
    unsigned s = 0;
    for (int i = 0; i < NB; ++i) s += hist[(size_t)i * BARR + b];
    total[b] = s;
}

__global__ void k_scanbase(const unsigned* __restrict__ total, unsigned* __restrict__ base) {
    __shared__ unsigned sh[BARR];
    int t = threadIdx.x;
    unsigned v = total[t];
    sh[t] = v;
    __syncthreads();
    for (int off = 1; off < BARR; off <<= 1) {
        unsigned x = 0;
        if (t >= off) x = sh[t - off];
        __syncthreads();
        sh[t] += x;
        __syncthreads();
    }
    base[t] = sh[t] - v;   // exclusive scan
}

__global__ void k_off(unsigned* __restrict__ hist, const unsigned* __restrict__ base) {
    int b = blockIdx.x * 256 + threadIdx.x;
    if (b >= BARR) return;
    unsigned run = base[b];
    for (int i = 0; i < NB; ++i) {
        size_t idx = (size_t)i * BARR + b;
        unsigned v = hist[idx];
        hist[idx] = run;    // hist becomes per-block scatter offsets, in place
        run += v;
    }
}

// pack: bits 0..17 = src (N<2^18), bits 24..31 = dst & 255
__global__ void k_part(const int* __restrict__ src, const int* __restrict__ dst,
                       const unsigned* __restrict__ off, unsigned* __restrict__ part) {
    __shared__ unsigned loff[BARR];
    const unsigned* o = off + (size_t)blockIdx.x * BARR;
    for (int j = threadIdx.x; j < BARR; j += 256) loff[j] = o[j];
    __syncthreads();
    int beg = blockIdx.x * CHUNK;
    int end = min(beg + CHUNK, N_EDGES);
    for (int e = beg + threadIdx.x; e < end; e += 256) {
        unsigned d = (unsigned)dst[e];
        unsigned s = (unsigned)src[e];
        unsigned pos = atomicAdd(&loff[d >> 8], 1u);   // LDS atomic, consecutive slots
        part[pos] = s | ((d & 255u) << 24);
    }
}

// deg per node (LDS counts) fused with dinv = rsqrt(deg), xs = x*dinv
__global__ void k_deg_dinv(const unsigned* __restrict__ part,
                           const unsigned* __restrict__ base, const unsigned* __restrict__ total,
                           const float* __restrict__ x,
                           float* __restrict__ dinv, float* __restrict__ xs) {
    __shared__ unsigned cnt[256];
    cnt[threadIdx.x] = 0;
    __syncthreads();
    unsigned st = base[blockIdx.x], tot = total[blockIdx.x];
    for (unsigned k = threadIdx.x; k < tot; k += 256)
        atomicAdd(&cnt[part[st + k] >> 24], 1u);
    __syncthreads();
    int n = blockIdx.x * 256 + threadIdx.x;
    if (n < N_NODES) {
        float di = rsqrtf((float)cnt[threadIdx.x] + 1.0f);  // +1 self-loop
        dinv[n] = di;
        xs[n] = x[n] * di;
    }
}

// layer-1 aggregation (LDS acc) fused with the 16-wide MLP epilogue:
// s = dinv*(acc + xs_self); t = sum relu(s*W1+b1)*W2; u = t*dinv; out = b2 + t*dinv^2
__global__ void k_agg1(const unsigned* __restrict__ part,
                       const unsigned* __restrict__ base, const unsigned* __restrict__ total,
                       const float* __restrict__ xs, const float* __restrict__ dinv,
                       const float* __restrict__ W1, const float* __restrict__ b1,
                       const float* __restrict__ W2, const float* __restrict__ b2,
                       float* __restrict__ u, float* __restrict__ out) {
    __shared__ float acc[256];
    acc[threadIdx.x] = 0.f;
    __syncthreads();
    unsigned st = base[blockIdx.x], tot = total[blockIdx.x];
    for (unsigned k = threadIdx.x; k < tot; k += 256) {
        unsigned p = part[st + k];
        atomicAdd(&acc[p >> 24], xs[p & 0x3FFFFu]);
    }
    __syncthreads();
    int n = blockIdx.x * 256 + threadIdx.x;
    if (n < N_NODES) {
        float di = dinv[n];
        float sv = di * (acc[threadIdx.x] + xs[n]);
        float t = 0.f;
        #pragma unroll
        for (int k = 0; k < 16; ++k)
            t = fmaf(fmaxf(fmaf(sv, W1[k], b1[k]), 0.f), W2[k], t);
        u[n] = t * di;
        out[n] = b2[0] + t * di * di;   // layer-2 self-loop + bias
    }
}

// layer-2 aggregation: out += dinv * sum(u[src])
__global__ void k_agg2(const unsigned* __restrict__ part,
                       const unsigned* __restrict__ base, const unsigned* __restrict__ total,
                       const float* __restrict__ u, const float* __restrict__ dinv,
                       float* __restrict__ out) {
    __shared__ float acc[256];
    acc[threadIdx.x] = 0.f;
    __syncthreads();
    unsigned st = base[blockIdx.x], tot = total[blockIdx.x];
    for (unsigned k = threadIdx.x; k < tot; k += 256) {
        unsigned p = part[st + k];
        atomicAdd(&acc[p >> 24], u[p & 0x3FFFFu]);
    }
    __syncthreads();
    int n = blockIdx.x * 256 + threadIdx.x;
    if (n < N_NODES) out[n] += dinv[n] * acc[threadIdx.x];
}

// ---- fallback path (round-1, device atomics) if ws is too small ----
__global__ void f_init(float* __restrict__ deg) {
    int n = blockIdx.x * blockDim.x + threadIdx.x;
    if (n < N_NODES) deg[n] = 1.0f;
}
__global__ void f_deg(const int* __restrict__ dst, float* __restrict__ deg) {
    int e = blockIdx.x * blockDim.x + threadIdx.x;
    if (e < N_EDGES) atomicAdd(&deg[dst[e]], 1.0f);
}
__global__ void f_node1(const float* __restrict__ x, const float* __restrict__ deg,
                        float* __restrict__ dinv, float* __restrict__ xs,
                        float* __restrict__ s) {
    int n = blockIdx.x * blockDim.x + threadIdx.x;
    if (n < N_NODES) {
        float di = rsqrtf(deg[n]);
        float xv = x[n];
        dinv[n] = di; xs[n] = xv * di; s[n] = xv * di * di;
    }
}
__global__ void f_sc1(const int* __restrict__ src, const int* __restrict__ dst,
                      const float* __restrict__ xs, const float* __restrict__ dinv,
                      float* __restrict__ s) {
    int e = blockIdx.x * blockDim.x + threadIdx.x;
    if (e < N_EDGES) atomicAdd(&s[dst[e]], xs[src[e]] * dinv[dst[e]]);
}
__global__ void f_node2(const float* __restrict__ s, const float* __restrict__ dinv,
                        const float* __restrict__ W1, const float* __restrict__ b1,
                        const float* __restrict__ W2, const float* __restrict__ b2,
                        float* __restrict__ u, float* __restrict__ out) {
    int n = blockIdx.x * blockDim.x + threadIdx.x;
    if (n < N_NODES) {
        float sv = s[n], acc = 0.0f;
        #pragma unroll
        for (int k = 0; k < 16; ++k)
            acc = fmaf(fmaxf(fmaf(sv, W1[k], b1[k]), 0.f), W2[k], acc);
        float di = dinv[n];
        u[n] = acc * di; out[n] = b2[0] + acc * di * di;
    }
}
__global__ void f_sc2(const int* __restrict__ src, const int* __restrict__ dst,
                      const float* __restrict__ u, const float* __restrict__ dinv,
                      float* __restrict__ out) {
    int e = blockIdx.x * blockDim.x + threadIdx.x;
    if (e < N_EDGES) atomicAdd(&out[dst[e]], u[src[e]] * dinv[dst[e]]);
}

extern "C" void kernel_launch(void* const* d_in, const int* in_sizes, int n_in,
                              void* d_out, int out_size, void* d_ws, size_t ws_size,
                              hipStream_t stream) {
    const float* x  = (const float*)d_in[0];
    const int*   ei = (const int*)d_in[1];
    const float* W1 = (const float*)d_in[2];
    const float* b1 = (const float*)d_in[3];
    const float* W2 = (const float*)d_in[4];
    const float* b2 = (const float*)d_in[5];
    float* out = (float*)d_out;
    const int* src = ei;
    const int* dst = ei + N_EDGES;

    const size_t need = ((size_t)NB * BARR + 2 * BARR + N_EDGES + 3 * N_NODES) * 4;

    if (ws_size >= need) {
        unsigned* hist  = (unsigned*)d_ws;
        unsigned* total = hist + (size_t)NB * BARR;
        unsigned* base  = total + BARR;
        unsigned* part  = base + BARR;
        float* dinv = (float*)(part + N_EDGES);
        float* xs   = dinv + N_NODES;
        float* u    = xs + N_NODES;

        k_hist    <<<NB, 256, 0, stream>>>(dst, hist);
        k_total   <<<BARR / 256, 256, 0, stream>>>(hist, total);
        k_scanbase<<<1, BARR, 0, stream>>>(total, base);
        k_off     <<<BARR / 256, 256, 0, stream>>>(hist, base);
        k_part    <<<NB, 256, 0, stream>>>(src, dst, hist, part);
        k_deg_dinv<<<NBUCK, 256, 0, stream>>>(part, base, total, x, dinv, xs);
        k_agg1    <<<NBUCK, 256, 0, stream>>>(part, base, total, xs, dinv, W1, b1, W2, b2, u, out);
        k_agg2    <<<NBUCK, 256, 0, stream>>>(part, base, total, u, dinv, out);
    } else {
        float* deg  = (float*)d_ws;
        float* dinv = deg + N_NODES;
        float* xs   = dinv + N_NODES;
        float* s    = xs + N_NODES;
        float* u    = deg;
        const int TB = 256;
        const int gn = (N_NODES + TB - 1) / TB;
        const int ge = (N_EDGES + TB - 1) / TB;
        f_init <<<gn, TB, 0, stream>>>(deg);
        f_deg  <<<ge, TB, 0, stream>>>(dst, deg);
        f_node1<<<gn, TB, 0, stream>>>(x, deg, dinv, xs, s);
        f_sc1  <<<ge, TB, 0, stream>>>(src, dst, xs, dinv, s);
        f_node2<<<gn, TB, 0, stream>>>(s, dinv, W1, b1, W2, b2, u, out);
        f_sc2  <<<ge, TB, 0, stream>>>(src, dst, u, dinv, out);
    }
}

// Round 3
// 169.606 us; speedup vs baseline: 4.4420x; 1.0086x over previous
//
#include <hip/hip_runtime.h>

static constexpr int N_NODES = 250000;
static constexpr int N_EDGES = 5000000;

// ---- fast path: counting-sort by dst>>9 into 512-node buckets ----
static constexpr int NB    = 512;                         // partition blocks
static constexpr int CHUNK = (N_EDGES + NB - 1) / NB;     // 9766
static constexpr int NBK   = 512;                         // bucket slots (dst>>9); 489 used
static constexpr int NBUCK = (N_NODES + 511) / 512;       // 489 consumer blocks
static constexpr int CAP   = 32;                          // LDS staging slots per bucket
static constexpr int TILE  = 2048;                        // edges per block-tile

// pack: bits 0..17 = src (N < 2^18), bits 20..28 = dst & 511
__device__ __forceinline__ unsigned pack_edge(unsigned s, unsigned d) {
    return s | ((d & 511u) << 20);
}

__global__ void k_hist(const int* __restrict__ dst, unsigned* __restrict__ hist) {
    __shared__ unsigned h[NBK];
    for (int j = threadIdx.x; j < NBK; j += 256) h[j] = 0;
    __syncthreads();
    int beg = blockIdx.x * CHUNK;
    int end = min(beg + CHUNK, N_EDGES);
    for (int e = beg + threadIdx.x; e < end; e += 256)
        atomicAdd(&h[((unsigned)dst[e]) >> 9], 1u);      // LDS atomic
    __syncthreads();
    unsigned* o = hist + (size_t)blockIdx.x * NBK;
    for (int j = threadIdx.x; j < NBK; j += 256) o[j] = h[j];
}

__global__ void k_total(const unsigned* __restrict__ hist, unsigned* __restrict__ total) {
    int b = blockIdx.x * 256 + threadIdx.x;
    if (b >= NBK) return;
    unsigned s = 0;
    for (int i = 0; i < NB; ++i) s += hist[(size_t)i * NBK + b];
    total[b] = s;
}

__global__ void k_scanbase(const unsigned* __restrict__ total, unsigned* __restrict__ base) {
    __shared__ unsigned sh[NBK];
    int t = threadIdx.x;
    unsigned v = total[t];
    sh[t] = v;
    __syncthreads();
    for (int off = 1; off < NBK; off <<= 1) {
        unsigned x = 0;
        if (t >= off) x = sh[t - off];
        __syncthreads();
        sh[t] += x;
        __syncthreads();
    }
    base[t] = sh[t] - v;   // exclusive scan
}

__global__ void k_off(unsigned* __restrict__ hist, const unsigned* __restrict__ base) {
    int b = blockIdx.x * 256 + threadIdx.x;
    if (b >= NBK) return;
    unsigned run = base[b];
    for (int i = 0; i < NB; ++i) {
        size_t idx = (size_t)i * NBK + b;
        unsigned v = hist[idx];
        hist[idx] = run;    // hist becomes per-(block,bucket) scatter cursor base
        run += v;
    }
}

// Partition with LDS staging: all global writes are coalesced 16-word groups
// (carry <16 residual across tiles); overflow path keeps correctness for any input.
__global__ void k_part(const int* __restrict__ src, const int* __restrict__ dst,
                       const unsigned* __restrict__ off, unsigned* __restrict__ part) {
    __shared__ unsigned stage[NBK][CAP];   // 64 KB
    __shared__ unsigned cnt[NBK];
    __shared__ unsigned goff[NBK];
    const unsigned* o = off + (size_t)blockIdx.x * NBK;
    for (int j = threadIdx.x; j < NBK; j += 256) { goff[j] = o[j]; cnt[j] = 0; }
    __syncthreads();
    int beg = blockIdx.x * CHUNK;
    int end = min(beg + CHUNK, N_EDGES);
    const int g  = threadIdx.x >> 4;   // 16 flush groups of 16 lanes
    const int gl = threadIdx.x & 15;
    for (int tb = beg; tb < end; tb += TILE) {
        int te = min(tb + TILE, end);
        // phase 1: stage into LDS bins
        for (int e = tb + threadIdx.x; e < te; e += 256) {
            unsigned d = (unsigned)dst[e];
            unsigned v = pack_edge((unsigned)src[e], d);
            unsigned b = d >> 9;
            unsigned pos = atomicAdd(&cnt[b], 1u);
            if (pos < CAP) stage[b][pos] = v;
            else part[atomicAdd(&goff[b], 1u)] = v;   // rare overflow: direct scatter
        }
        __syncthreads();
        const bool last = (te == end);
        // phase 2: coalesced flush of full 16-groups (plus residual on last tile)
        for (int b = g; b < NBK; b += 16) {
            unsigned n = min(cnt[b], (unsigned)CAP);
            unsigned nfull = n >> 4, rem = n & 15u;
            unsigned gbase = goff[b];
            for (unsigned k = 0; k < nfull; ++k)
                part[gbase + k * 16u + gl] = stage[b][k * 16u + gl];
            if (last) {
                if (gl < rem) part[gbase + nfull * 16u + gl] = stage[b][nfull * 16u + gl];
            } else {
                if (gl < rem) stage[b][gl] = stage[b][nfull * 16u + gl]; // nfull==0 -> no-op copy
            }
            if (gl == 0) {
                goff[b] = gbase + (last ? n : nfull * 16u);
                cnt[b]  = last ? 0u : rem;
            }
        }
        __syncthreads();
    }
}

// deg per node (LDS counts) fused with dinv = rsqrt(deg), xs = x*dinv
__global__ void k_deg_dinv(const unsigned* __restrict__ part,
                           const unsigned* __restrict__ base, const unsigned* __restrict__ total,
                           const float* __restrict__ x,
                           float* __restrict__ dinv, float* __restrict__ xs) {
    __shared__ unsigned cnt[512];
    cnt[threadIdx.x] = 0;
    __syncthreads();
    unsigned st = base[blockIdx.x], tot = total[blockIdx.x];
    for (unsigned k = threadIdx.x; k < tot; k += 512)
        atomicAdd(&cnt[(part[st + k] >> 20) & 511u], 1u);
    __syncthreads();
    int n = blockIdx.x * 512 + threadIdx.x;
    if (n < N_NODES) {
        float di = rsqrtf((float)cnt[threadIdx.x] + 1.0f);  // +1 self-loop
        dinv[n] = di;
        xs[n] = x[n] * di;
    }
}

// layer-1 aggregation + fused 16-wide MLP epilogue:
// s = dinv*(acc + xs_self); t = sum relu(s*W1+b1)*W2; u = t*dinv; out = b2 + t*dinv^2
__global__ void k_agg1(const unsigned* __restrict__ part,
                       const unsigned* __restrict__ base, const unsigned* __restrict__ total,
                       const float* __restrict__ xs, const float* __restrict__ dinv,
                       const float* __restrict__ W1, const float* __restrict__ b1,
                       const float* __restrict__ W2, const float* __restrict__ b2,
                       float* __restrict__ u, float* __restrict__ out) {
    __shared__ float acc[512];
    acc[threadIdx.x] = 0.f;
    __syncthreads();
    unsigned st = base[blockIdx.x], tot = total[blockIdx.x];
    for (unsigned k = threadIdx.x; k < tot; k += 512) {
        unsigned p = part[st + k];
        atomicAdd(&acc[(p >> 20) & 511u], xs[p & 0x3FFFFu]);
    }
    __syncthreads();
    int n = blockIdx.x * 512 + threadIdx.x;
    if (n < N_NODES) {
        float di = dinv[n];
        float sv = di * (acc[threadIdx.x] + xs[n]);
        float t = 0.f;
        #pragma unroll
        for (int k = 0; k < 16; ++k)
            t = fmaf(fmaxf(fmaf(sv, W1[k], b1[k]), 0.f), W2[k], t);
        u[n] = t * di;
        out[n] = b2[0] + t * di * di;   // layer-2 self-loop + bias
    }
}

// layer-2 aggregation: out += dinv * sum(u[src])
__global__ void k_agg2(const unsigned* __restrict__ part,
                       const unsigned* __restrict__ base, const unsigned* __restrict__ total,
                       const float* __restrict__ u, const float* __restrict__ dinv,
                       float* __restrict__ out) {
    __shared__ float acc[512];
    acc[threadIdx.x] = 0.f;
    __syncthreads();
    unsigned st = base[blockIdx.x], tot = total[blockIdx.x];
    for (unsigned k = threadIdx.x; k < tot; k += 512) {
        unsigned p = part[st + k];
        atomicAdd(&acc[(p >> 20) & 511u], u[p & 0x3FFFFu]);
    }
    __syncthreads();
    int n = blockIdx.x * 512 + threadIdx.x;
    if (n < N_NODES) out[n] += dinv[n] * acc[threadIdx.x];
}

// ---- fallback path (device atomics) if ws is too small ----
__global__ void f_init(float* __restrict__ deg) {
    int n = blockIdx.x * blockDim.x + threadIdx.x;
    if (n < N_NODES) deg[n] = 1.0f;
}
__global__ void f_deg(const int* __restrict__ dst, float* __restrict__ deg) {
    int e = blockIdx.x * blockDim.x + threadIdx.x;
    if (e < N_EDGES) atomicAdd(&deg[dst[e]], 1.0f);
}
__global__ void f_node1(const float* __restrict__ x, const float* __restrict__ deg,
                        float* __restrict__ dinv, float* __restrict__ xs,
                        float* __restrict__ s) {
    int n = blockIdx.x * blockDim.x + threadIdx.x;
    if (n < N_NODES) {
        float di = rsqrtf(deg[n]);
        float xv = x[n];
        dinv[n] = di; xs[n] = xv * di; s[n] = xv * di * di;
    }
}
__global__ void f_sc1(const int* __restrict__ src, const int* __restrict__ dst,
                      const float* __restrict__ xs, const float* __restrict__ dinv,
                      float* __restrict__ s) {
    int e = blockIdx.x * blockDim.x + threadIdx.x;
    if (e < N_EDGES) atomicAdd(&s[dst[e]], xs[src[e]] * dinv[dst[e]]);
}
__global__ void f_node2(const float* __restrict__ s, const float* __restrict__ dinv,
                        const float* __restrict__ W1, const float* __restrict__ b1,
                        const float* __restrict__ W2, const float* __restrict__ b2,
                        float* __restrict__ u, float* __restrict__ out) {
    int n = blockIdx.x * blockDim.x + threadIdx.x;
    if (n < N_NODES) {
        float sv = s[n], acc = 0.0f;
        #pragma unroll
        for (int k = 0; k < 16; ++k)
            acc = fmaf(fmaxf(fmaf(sv, W1[k], b1[k]), 0.f), W2[k], acc);
        float di = dinv[n];
        u[n] = acc * di; out[n] = b2[0] + acc * di * di;
    }
}
__global__ void f_sc2(const int* __restrict__ src, const int* __restrict__ dst,
                      const float* __restrict__ u, const float* __restrict__ dinv,
                      float* __restrict__ out) {
    int e = blockIdx.x * blockDim.x + threadIdx.x;
    if (e < N_EDGES) atomicAdd(&out[dst[e]], u[src[e]] * dinv[dst[e]]);
}

extern "C" void kernel_launch(void* const* d_in, const int* in_sizes, int n_in,
                              void* d_out, int out_size, void* d_ws, size_t ws_size,
                              hipStream_t stream) {
    const float* x  = (const float*)d_in[0];
    const int*   ei = (const int*)d_in[1];
    const float* W1 = (const float*)d_in[2];
    const float* b1 = (const float*)d_in[3];
    const float* W2 = (const float*)d_in[4];
    const float* b2 = (const float*)d_in[5];
    float* out = (float*)d_out;
    const int* src = ei;
    const int* dst = ei + N_EDGES;

    const size_t need = ((size_t)NB * NBK + 2 * NBK + N_EDGES + 3 * N_NODES) * 4;

    if (ws_size >= need) {
        unsigned* hist  = (unsigned*)d_ws;
        unsigned* total = hist + (size_t)NB * NBK;
        unsigned* base  = total + NBK;
        unsigned* part  = base + NBK;
        float* dinv = (float*)(part + N_EDGES);
        float* xs   = dinv + N_NODES;
        float* u    = xs + N_NODES;

        k_hist    <<<NB, 256, 0, stream>>>(dst, hist);
        k_total   <<<NBK / 256, 256, 0, stream>>>(hist, total);
        k_scanbase<<<1, NBK, 0, stream>>>(total, base);
        k_off     <<<NBK / 256, 256, 0, stream>>>(hist, base);
        k_part    <<<NB, 256, 0, stream>>>(src, dst, hist, part);
        k_deg_dinv<<<NBUCK, 512, 0, stream>>>(part, base, total, x, dinv, xs);
        k_agg1    <<<NBUCK, 512, 0, stream>>>(part, base, total, xs, dinv, W1, b1, W2, b2, u, out);
        k_agg2    <<<NBUCK, 512, 0, stream>>>(part, base, total, u, dinv, out);
    } else {
        float* deg  = (float*)d_ws;
        float* dinv = deg + N_NODES;
        float* xs   = dinv + N_NODES;
        float* s    = xs + N_NODES;
        float* u    = deg;
        const int TB = 256;
        const int gn = (N_NODES + TB - 1) / TB;
        const int ge = (N_EDGES + TB - 1) / TB;
        f_init <<<gn, TB, 0, stream>>>(deg);
        f_deg  <<<ge, TB, 0, stream>>>(dst, deg);
        f_node1<<<gn, TB, 0, stream>>>(x, deg, dinv, xs, s);
        f_sc1  <<<ge, TB, 0, stream>>>(src, dst, xs, dinv, s);
        f_node2<<<gn, TB, 0, stream>>>(s, dinv, W1, b1, W2, b2, u, out);
        f_sc2  <<<ge, TB, 0, stream>>>(src, dst, u, dinv, out);
    }
}

// Round 4
// 132.259 us; speedup vs baseline: 5.6963x; 1.2824x over previous
//
#include <hip/hip_runtime.h>

static constexpr int N_NODES = 250000;
static constexpr int N_EDGES = 5000000;

// ---- fast path: counting-sort by dst>>9 into 512-node buckets ----
static constexpr int NB    = 512;                       // partition blocks
static constexpr int CHUNK = 9768;                      // per-block edges, multiple of 4; NB*CHUNK >= N_EDGES
static constexpr int NBK   = 512;                       // bucket slots (dst>>9); 489 used
static constexpr int NBUCK = (N_NODES + 511) / 512;     // 489 consumer blocks
static constexpr int CAP   = 32;                        // LDS staging slots per bucket
static constexpr int TILE  = 2048;                      // edges per block-tile = 512 thr * 4

// pack: bits 0..17 = src (N < 2^18), bits 20..28 = dst & 511
__device__ __forceinline__ unsigned pack_edge(unsigned s, unsigned d) {
    return s | ((d & 511u) << 20);
}

__global__ void k_hist(const int* __restrict__ dst, unsigned* __restrict__ hist) {
    __shared__ unsigned h[NBK];
    for (int j = threadIdx.x; j < NBK; j += 512) h[j] = 0;
    __syncthreads();
    int beg = blockIdx.x * CHUNK;
    int end = min(beg + CHUNK, N_EDGES);
    for (int e = beg + (int)threadIdx.x * 4; e < end; e += TILE) {
        if (e + 4 <= end) {
            int4 d4 = *(const int4*)(dst + e);
            atomicAdd(&h[((unsigned)d4.x) >> 9], 1u);
            atomicAdd(&h[((unsigned)d4.y) >> 9], 1u);
            atomicAdd(&h[((unsigned)d4.z) >> 9], 1u);
            atomicAdd(&h[((unsigned)d4.w) >> 9], 1u);
        } else {
            for (int j = 0; j < 4 && e + j < end; ++j)
                atomicAdd(&h[((unsigned)dst[e + j]) >> 9], 1u);
        }
    }
    __syncthreads();
    unsigned* o = hist + (size_t)blockIdx.x * NBK;
    for (int j = threadIdx.x; j < NBK; j += 512) o[j] = h[j];
}

__global__ void k_total(const unsigned* __restrict__ hist, unsigned* __restrict__ total) {
    int b = blockIdx.x * 256 + threadIdx.x;
    if (b >= NBK) return;
    unsigned s = 0;
    for (int i = 0; i < NB; ++i) s += hist[(size_t)i * NBK + b];
    total[b] = s;
}

__global__ void k_scanbase(const unsigned* __restrict__ total, unsigned* __restrict__ base) {
    __shared__ unsigned sh[NBK];
    int t = threadIdx.x;
    unsigned v = total[t];
    sh[t] = v;
    __syncthreads();
    for (int off = 1; off < NBK; off <<= 1) {
        unsigned x = 0;
        if (t >= off) x = sh[t - off];
        __syncthreads();
        sh[t] += x;
        __syncthreads();
    }
    base[t] = sh[t] - v;   // exclusive scan
}

__global__ void k_off(unsigned* __restrict__ hist, const unsigned* __restrict__ base) {
    int b = blockIdx.x * 256 + threadIdx.x;
    if (b >= NBK) return;
    unsigned run = base[b];
    for (int i = 0; i < NB; ++i) {
        size_t idx = (size_t)i * NBK + b;
        unsigned v = hist[idx];
        hist[idx] = run;    // hist becomes per-(block,bucket) scatter cursor base
        run += v;
    }
}

// Partition: LDS-staged, XOR-swizzled bins, coalesced 16-word flushes.
__global__ void k_part(const int* __restrict__ src, const int* __restrict__ dst,
                       const unsigned* __restrict__ off, unsigned* __restrict__ part) {
    __shared__ unsigned stage[NBK][CAP];   // 64 KB, swizzled: slot = pos ^ (b&31)
    __shared__ unsigned cnt[NBK];
    __shared__ unsigned goff[NBK];
    const unsigned* o = off + (size_t)blockIdx.x * NBK;
    for (int j = threadIdx.x; j < NBK; j += 512) { goff[j] = o[j]; cnt[j] = 0; }
    __syncthreads();
    int beg = blockIdx.x * CHUNK;
    int end = min(beg + CHUNK, N_EDGES);
    const int g  = threadIdx.x >> 4;   // 32 flush groups of 16 lanes
    const int gl = threadIdx.x & 15;
    for (int tb = beg; tb < end; tb += TILE) {
        int te = min(tb + TILE, end);
        // phase 1: stage into LDS bins (one vectorized step covers the tile)
        {
            int e = tb + (int)threadIdx.x * 4;
            int s0, s1, s2, s3, d0, d1, d2, d3, cnt4 = 0;
            if (e + 4 <= te) {
                int4 d4 = *(const int4*)(dst + e);
                int4 s4 = *(const int4*)(src + e);
                d0 = d4.x; d1 = d4.y; d2 = d4.z; d3 = d4.w;
                s0 = s4.x; s1 = s4.y; s2 = s4.z; s3 = s4.w;
                cnt4 = 4;
            } else {
                int m = te - e;
                cnt4 = m < 0 ? 0 : m;
                if (cnt4 > 0) { d0 = dst[e];     s0 = src[e]; }
                if (cnt4 > 1) { d1 = dst[e + 1]; s1 = src[e + 1]; }
                if (cnt4 > 2) { d2 = dst[e + 2]; s2 = src[e + 2]; }
                if (cnt4 > 3) { d3 = dst[e + 3]; s3 = src[e + 3]; }
            }
            #pragma unroll
            for (int j = 0; j < 4; ++j) {
                if (j >= cnt4) break;
                int dd = j == 0 ? d0 : j == 1 ? d1 : j == 2 ? d2 : d3;
                int ss = j == 0 ? s0 : j == 1 ? s1 : j == 2 ? s2 : s3;
                unsigned b = ((unsigned)dd) >> 9;
                unsigned v = pack_edge((unsigned)ss, (unsigned)dd);
                unsigned pos = atomicAdd(&cnt[b], 1u);
                if (pos < CAP) stage[b][pos ^ (b & 31u)] = v;
                else part[atomicAdd(&goff[b], 1u)] = v;   // rare overflow
            }
        }
        __syncthreads();
        const bool last = (te == end);
        // phase 2: coalesced flush of full 16-groups (residual carried across tiles)
        for (int b = g; b < NBK; b += 32) {
            const unsigned c = (unsigned)b & 31u;
            unsigned n = min(cnt[b], (unsigned)CAP);
            unsigned nfull = n >> 4, rem = n & 15u;
            unsigned gbase = goff[b];
            for (unsigned k = 0; k < nfull; ++k)
                part[gbase + k * 16u + gl] = stage[b][(k * 16u + gl) ^ c];
            if (last) {
                if (gl < rem) part[gbase + nfull * 16u + gl] = stage[b][(nfull * 16u + gl) ^ c];
            } else {
                if (gl < rem) {
                    unsigned tmp = stage[b][(nfull * 16u + gl) ^ c];
                    stage[b][(unsigned)gl ^ c] = tmp;   // disjoint src/dst sets (proof: XOR halves)
                }
            }
            if (gl == 0) {
                goff[b] = gbase + (last ? n : nfull * 16u);
                cnt[b]  = last ? 0u : rem;
            }
        }
        __syncthreads();
    }
}

// per-edge consumer loop: aligned uint4 body + scalar head/tail
#define BUCKET_EDGE_LOOP(EDGE_OP)                                              \
    unsigned st = base[blockIdx.x], tot = total[blockIdx.x];                   \
    unsigned en = st + tot;                                                    \
    unsigned a0 = (st + 3u) & ~3u; if (a0 > en) a0 = en;                       \
    unsigned a1 = en & ~3u;        if (a1 < a0) a1 = a0;                       \
    if (st + threadIdx.x < a0) { unsigned p = part[st + threadIdx.x]; EDGE_OP(p); } \
    for (unsigned k = a0 + threadIdx.x * 4u; k < a1; k += 2048u) {             \
        uint4 q = *(const uint4*)(part + k);                                   \
        EDGE_OP(q.x); EDGE_OP(q.y); EDGE_OP(q.z); EDGE_OP(q.w);                \
    }                                                                          \
    if (a1 + threadIdx.x < en) { unsigned p = part[a1 + threadIdx.x]; EDGE_OP(p); }

// deg per node (LDS counts) fused with dinv = rsqrt(deg), xs = x*dinv
__global__ void k_deg_dinv(const unsigned* __restrict__ part,
                           const unsigned* __restrict__ base, const unsigned* __restrict__ total,
                           const float* __restrict__ x,
                           float* __restrict__ dinv, float* __restrict__ xs) {
    __shared__ unsigned cnt[512];
    cnt[threadIdx.x] = 0;
    __syncthreads();
    #define DEG_OP(p) atomicAdd(&cnt[((p) >> 20) & 511u], 1u)
    BUCKET_EDGE_LOOP(DEG_OP)
    #undef DEG_OP
    __syncthreads();
    int n = blockIdx.x * 512 + threadIdx.x;
    if (n < N_NODES) {
        float di = rsqrtf((float)cnt[threadIdx.x] + 1.0f);  // +1 self-loop
        dinv[n] = di;
        xs[n] = x[n] * di;
    }
}

// layer-1 aggregation + fused 16-wide MLP epilogue:
// s = dinv*(acc + xs_self); t = sum relu(s*W1+b1)*W2; u = t*dinv; out = b2 + t*dinv^2
__global__ void k_agg1(const unsigned* __restrict__ part,
                       const unsigned* __restrict__ base, const unsigned* __restrict__ total,
                       const float* __restrict__ xs, const float* __restrict__ dinv,
                       const float* __restrict__ W1, const float* __restrict__ b1,
                       const float* __restrict__ W2, const float* __restrict__ b2,
                       float* __restrict__ u, float* __restrict__ out) {
    __shared__ float acc[512];
    acc[threadIdx.x] = 0.f;
    __syncthreads();
    #define AGG1_OP(p) atomicAdd(&acc[((p) >> 20) & 511u], xs[(p) & 0x3FFFFu])
    BUCKET_EDGE_LOOP(AGG1_OP)
    #undef AGG1_OP
    __syncthreads();
    int n = blockIdx.x * 512 + threadIdx.x;
    if (n < N_NODES) {
        float di = dinv[n];
        float sv = di * (acc[threadIdx.x] + xs[n]);
        float t = 0.f;
        #pragma unroll
        for (int k = 0; k < 16; ++k)
            t = fmaf(fmaxf(fmaf(sv, W1[k], b1[k]), 0.f), W2[k], t);
        u[n] = t * di;
        out[n] = b2[0] + t * di * di;   // layer-2 self-loop + bias
    }
}

// layer-2 aggregation: out += dinv * sum(u[src])
__global__ void k_agg2(const unsigned* __restrict__ part,
                       const unsigned* __restrict__ base, const unsigned* __restrict__ total,
                       const float* __restrict__ u, const float* __restrict__ dinv,
                       float* __restrict__ out) {
    __shared__ float acc[512];
    acc[threadIdx.x] = 0.f;
    __syncthreads();
    #define AGG2_OP(p) atomicAdd(&acc[((p) >> 20) & 511u], u[(p) & 0x3FFFFu])
    BUCKET_EDGE_LOOP(AGG2_OP)
    #undef AGG2_OP
    __syncthreads();
    int n = blockIdx.x * 512 + threadIdx.x;
    if (n < N_NODES) out[n] += dinv[n] * acc[threadIdx.x];
}

// ---- fallback path (device atomics) if ws is too small ----
__global__ void f_init(float* __restrict__ deg) {
    int n = blockIdx.x * blockDim.x + threadIdx.x;
    if (n < N_NODES) deg[n] = 1.0f;
}
__global__ void f_deg(const int* __restrict__ dst, float* __restrict__ deg) {
    int e = blockIdx.x * blockDim.x + threadIdx.x;
    if (e < N_EDGES) atomicAdd(&deg[dst[e]], 1.0f);
}
__global__ void f_node1(const float* __restrict__ x, const float* __restrict__ deg,
                        float* __restrict__ dinv, float* __restrict__ xs,
                        float* __restrict__ s) {
    int n = blockIdx.x * blockDim.x + threadIdx.x;
    if (n < N_NODES) {
        float di = rsqrtf(deg[n]);
        float xv = x[n];
        dinv[n] = di; xs[n] = xv * di; s[n] = xv * di * di;
    }
}
__global__ void f_sc1(const int* __restrict__ src, const int* __restrict__ dst,
                      const float* __restrict__ xs, const float* __restrict__ dinv,
                      float* __restrict__ s) {
    int e = blockIdx.x * blockDim.x + threadIdx.x;
    if (e < N_EDGES) atomicAdd(&s[dst[e]], xs[src[e]] * dinv[dst[e]]);
}
__global__ void f_node2(const float* __restrict__ s, const float* __restrict__ dinv,
                        const float* __restrict__ W1, const float* __restrict__ b1,
                        const float* __restrict__ W2, const float* __restrict__ b2,
                        float* __restrict__ u, float* __restrict__ out) {
    int n = blockIdx.x * blockDim.x + threadIdx.x;
    if (n < N_NODES) {
        float sv = s[n], acc = 0.0f;
        #pragma unroll
        for (int k = 0; k < 16; ++k)
            acc = fmaf(fmaxf(fmaf(sv, W1[k], b1[k]), 0.f), W2[k], acc);
        float di = dinv[n];
        u[n] = acc * di; out[n] = b2[0] + acc * di * di;
    }
}
__global__ void f_sc2(const int* __restrict__ src, const int* __restrict__ dst,
                      const float* __restrict__ u, const float* __restrict__ dinv,
                      float* __restrict__ out) {
    int e = blockIdx.x * blockDim.x + threadIdx.x;
    if (e < N_EDGES) atomicAdd(&out[dst[e]], u[src[e]] * dinv[dst[e]]);
}

extern "C" void kernel_launch(void* const* d_in, const int* in_sizes, int n_in,
                              void* d_out, int out_size, void* d_ws, size_t ws_size,
                              hipStream_t stream) {
    const float* x  = (const float*)d_in[0];
    const int*   ei = (const int*)d_in[1];
    const float* W1 = (const float*)d_in[2];
    const float* b1 = (const float*)d_in[3];
    const float* W2 = (const float*)d_in[4];
    const float* b2 = (const float*)d_in[5];
    float* out = (float*)d_out;
    const int* src = ei;
    const int* dst = ei + N_EDGES;

    const size_t need = ((size_t)NB * NBK + 2 * NBK + N_EDGES + 3 * N_NODES) * 4;

    if (ws_size >= need) {
        unsigned* hist  = (unsigned*)d_ws;
        unsigned* total = hist + (size_t)NB * NBK;
        unsigned* base  = total + NBK;
        unsigned* part  = base + NBK;
        float* dinv = (float*)(part + N_EDGES);
        float* xs   = dinv + N_NODES;
        float* u    = xs + N_NODES;

        k_hist    <<<NB, 512, 0, stream>>>(dst, hist);
        k_total   <<<NBK / 256, 256, 0, stream>>>(hist, total);
        k_scanbase<<<1, NBK, 0, stream>>>(total, base);
        k_off     <<<NBK / 256, 256, 0, stream>>>(hist, base);
        k_part    <<<NB, 512, 0, stream>>>(src, dst, hist, part);
        k_deg_dinv<<<NBUCK, 512, 0, stream>>>(part, base, total, x, dinv, xs);
        k_agg1    <<<NBUCK, 512, 0, stream>>>(part, base, total, xs, dinv, W1, b1, W2, b2, u, out);
        k_agg2    <<<NBUCK, 512, 0, stream>>>(part, base, total, u, dinv, out);
    } else {
        float* deg  = (float*)d_ws;
        float* dinv = deg + N_NODES;
        float* xs   = dinv + N_NODES;
        float* s    = xs + N_NODES;
        float* u    = deg;
        const int TB = 256;
        const int gn = (N_NODES + TB - 1) / TB;
        const int ge = (N_EDGES + TB - 1) / TB;
        f_init <<<gn, TB, 0, stream>>>(deg);
        f_deg  <<<ge, TB, 0, stream>>>(dst, deg);
        f_node1<<<gn, TB, 0, stream>>>(x, deg, dinv, xs, s);
        f_sc1  <<<ge, TB, 0, stream>>>(src, dst, xs, dinv, s);
        f_node2<<<gn, TB, 0, stream>>>(s, dinv, W1, b1, W2, b2, u, out);
        f_sc2  <<<ge, TB, 0, stream>>>(src, dst, u, dinv, out);
    }
}